// Round 8
// baseline (1682.349 us; speedup 1.0000x reference)
//
#include <hip/hip_runtime.h>
#include <hip/hip_bf16.h>
#include <hip/hip_fp16.h>

// CellTrack GNN, MI355X — R21: row-split wave mapping -> NT 1-2 -> 4 (LDS-BW fix).
// R20 (867us): k_edge_mlp 374us, MFMA-busy (24% x 374 = 90us) == ideal 82us ->
// the GEMM loop sits AT its LDS-BW ceiling (MfmaUtil_max ~= NT/9.9; NT was 2
// on GEMM1 and 1 on the 128-wide GEMMs). Prefetch never helped because LDS
// bandwidth per MFMA, not latency, binds.
// R21: mfma_gemm waves = RS row-groups x CS col-groups. GEMM1/MP1: RS=2 ->
// RT2/NT4; 128-wide GEMMs: RS=4 -> RT1/NT4; C1 RS=4 -> NT2; nenc-G1 RS=2 ->
// NT8 (CHUNK=1). B re-read RS-x from L2 (WT L2-resident, FETCH unchanged).
// ws: AGG|EB|WT|XH|XNH|X1P|X2H|BF|CNT|POS|TEX|ES|ET|OID|BS|BSSE ~201MB.

using fp16 = __half;
typedef _Float16 h16;
typedef _Float16 f16x8 __attribute__((ext_vector_type(8)));
typedef _Float16 h16x2 __attribute__((ext_vector_type(2)));
typedef short s16x8 __attribute__((ext_vector_type(8)));
typedef float f32x4 __attribute__((ext_vector_type(4)));

#define NN 50000
#define EE 500000
#define EPSC 1e-8f
#define SCAN_B 196   // ceil(NN/256)

__device__ __forceinline__ float reluf(float v){ return v > 0.f ? v : 0.f; }

// fp16-pair dot with fp32 accumulate (v_dot2_f32_f16); products exact in fp32
__device__ __forceinline__ float dot8(const f16x8 a, const f16x8 b, float acc)
{
#pragma unroll
  for (int i = 0; i < 4; ++i) {
    const h16x2 av = {a[2 * i], a[2 * i + 1]};
    const h16x2 bv = {b[2 * i], b[2 * i + 1]};
    acc = __builtin_amdgcn_fdot2(av, bv, acc, false);
  }
  return acc;
}

// packed |a-b|: v_pk sub + bitmask (== RN(a-b) then clear sign, same as fp32 path)
__device__ __forceinline__ f16x8 absdiff8(const f16x8 a, const f16x8 b)
{
  const f16x8 d = a - b;
  s16x8 di = __builtin_bit_cast(s16x8, d);
  di &= (short)0x7fff;
  return __builtin_bit_cast(f16x8, di);
}

// WT sub-buffer offsets (halves)
#define OFF_E1   0         // [256][544]  (527 real, permuted col order)
#define OFF_E2   139264    // [128][256]
#define OFF_MSG  172032    // [128][256]  ([e|xs] order)
#define OFF_NODE 204800    // [128][256]
#define OFF_MP1  237568    // [256][384]
#define OFF_MP2  335872    // [128][256]
#define OFF_C1   368640    // [64][128]
#define OFF_N1   376832    // [512][160]  block-diag [Wh1 | Wl1]
#define OFF_N2   458752    // [128][512]  block-diag [Wh2 ; Wl2]
#define WT_TOTAL 524288
// fused biases (fp32, after WT): BF[0..511]=[bh1|bl1], BF[512..639]=[bh2|bl2]
#define BF_TOTAL 640

// ---------------------------------------------------------------------------
// k_prep: fp32 weights -> fp16 transposed [n][kP] (zero-pad k >= kreal).
// ---------------------------------------------------------------------------
__global__ __launch_bounds__(256) void k_prep(
    const float* __restrict__ We1, const float* __restrict__ We2,
    const float* __restrict__ Wmsg, const float* __restrict__ Wnode,
    const float* __restrict__ Wmp1, const float* __restrict__ Wmp2,
    const float* __restrict__ Wc1,
    const float* __restrict__ Wh1, const float* __restrict__ Wl1,
    const float* __restrict__ Wh2, const float* __restrict__ Wl2,
    const float* __restrict__ bh1, const float* __restrict__ bl1,
    const float* __restrict__ bh2, const float* __restrict__ bl2,
    h16* __restrict__ WT, float* __restrict__ BF)
{
  int idx = blockIdx.x * 256 + threadIdx.x;
  if (idx >= WT_TOTAL) {
    const int b = idx - WT_TOTAL;
    if (b < 512) BF[b] = (b < 256) ? bh1[b] : bl1[b - 256];
    else if (b < BF_TOTAL) {
      const int c = b - 512;
      BF[b] = (c < 32) ? bh2[c] : bl2[c - 32];
    }
    return;
  }
  h16 v;
  if (idx < OFF_E2) {
    const int L = idx, n = L / 544, k = L % 544;
    int r;
    if      (k < 128) r = 142 + k;
    else if (k < 256) r = 270 + (k - 128);
    else if (k < 384) r = 398 + (k - 256);
    else if (k < 512) r = 13 + (k - 384);
    else if (k < 525) r = k - 512;
    else if (k == 528) r = 141;
    else if (k == 529) r = 526;
    else r = -1;
    v = (h16)((r >= 0) ? We1[r * 256 + n] : 0.f);
  } else if (idx < OFF_MSG) {
    const int L = idx - OFF_E2, n = L >> 8, k = L & 255;
    v = (h16)We2[k * 128 + n];
  } else if (idx < OFF_NODE) {
    const int L = idx - OFF_MSG, n = L >> 8, k = L & 255;
    const int ko = (k < 128) ? (128 + k) : (k - 128);   // [e|xs] order
    v = (h16)Wmsg[ko * 128 + n];
  } else if (idx < OFF_MP1) {
    const int L = idx - OFF_NODE, n = L >> 8, k = L & 255;
    v = (h16)Wnode[k * 128 + n];
  } else if (idx < OFF_MP2) {
    const int L = idx - OFF_MP1, n = L / 384, k = L % 384;
    v = (h16)Wmp1[k * 256 + n];
  } else if (idx < OFF_C1) {
    const int L = idx - OFF_MP2, n = L >> 8, k = L & 255;
    v = (h16)Wmp2[k * 128 + n];
  } else if (idx < OFF_N1) {
    const int L = idx - OFF_C1, n = L >> 7, k = L & 127;
    v = (h16)Wc1[k * 64 + n];
  } else if (idx < OFF_N2) {
    const int L = idx - OFF_N1, n = L / 160, k = L % 160;
    float f = 0.f;
    if (n < 256) { if (k < 13) f = Wh1[k * 256 + n]; }
    else { if (k >= 16 && k < 144) f = Wl1[(k - 16) * 256 + (n - 256)]; }
    v = (h16)f;
  } else {
    const int L = idx - OFF_N2, n = L >> 9, k = L & 511;
    float f = 0.f;
    if (n < 32) { if (k < 256) f = Wh2[k * 32 + n]; }
    else { if (k >= 256) f = Wl2[(k - 256) * 96 + (n - 32)]; }
    v = (h16)f;
  }
  WT[idx] = v;
}

// k_cvt: x1 -> fp16 mirror padded to 16/row, x2 -> fp16; + trg histogram.
__global__ __launch_bounds__(256) void k_cvt(
    const float* __restrict__ x1, const float* __restrict__ x2,
    const int* __restrict__ ei,
    h16* __restrict__ X1P, h16* __restrict__ X2H, int* __restrict__ CNT)
{
  const int idx = blockIdx.x * 256 + threadIdx.x;
  if (idx < EE) atomicAdd(&CNT[ei[EE + idx]], 1);
  if (idx < NN * 16) {
    const int nn = idx >> 4, j = idx & 15;
    X1P[idx] = (h16)((j < 13) ? x1[nn * 13 + j] : 0.f);
  }
  const int i2 = idx - NN * 16;
  if (i2 >= 0 && i2 < NN * 128) X2H[i2] = (h16)x2[i2];
}

// --------------------------- hierarchical scan -----------------------------
__global__ __launch_bounds__(256) void k_scanA(
    const int* __restrict__ CNT, int* __restrict__ TEX, int* __restrict__ BS)
{
  __shared__ int sd[256];
  const int tid = threadIdx.x;
  const int i = blockIdx.x * 256 + tid;
  const int v = (i < NN) ? CNT[i] : 0;
  sd[tid] = v;
  __syncthreads();
  for (int off = 1; off < 256; off <<= 1) {
    const int x = (tid >= off) ? sd[tid - off] : 0;
    __syncthreads();
    sd[tid] += x;
    __syncthreads();
  }
  if (i < NN) TEX[i] = sd[tid] - v;              // tile-exclusive prefix
  if (tid == 255) BS[blockIdx.x] = sd[255];      // tile total
}

__global__ __launch_bounds__(256) void k_scanB(
    const int* __restrict__ BS, int* __restrict__ BSSE)
{
  __shared__ int sd[256];
  const int tid = threadIdx.x;
  const int v = (tid < SCAN_B) ? BS[tid] : 0;
  sd[tid] = v;
  __syncthreads();
  for (int off = 1; off < 256; off <<= 1) {
    const int x = (tid >= off) ? sd[tid - off] : 0;
    __syncthreads();
    sd[tid] += x;
    __syncthreads();
  }
  if (tid < SCAN_B) BSSE[tid] = sd[tid] - v;     // exclusive tile base
}

__global__ __launch_bounds__(256) void k_scatter(
    const int* __restrict__ ei, const int* __restrict__ TEX,
    const int* __restrict__ BSSE, int* __restrict__ POS,
    int* __restrict__ ES, int* __restrict__ ET, int* __restrict__ OID)
{
  const int e = blockIdx.x * 256 + threadIdx.x;
  if (e >= EE) return;
  const int t = ei[EE + e];
  const int p = atomicAdd(&POS[t], 1);
  const int idx = BSSE[t >> 8] + TEX[t] + p;
  ES[idx] = ei[e];
  ET[idx] = t;
  OID[idx] = e;
}

// ---------------------------------------------------------------------------
// MFMA GEMM: C[ROWS][UDIM] = act(A[ROWS][KP] @ WT^T + b).
// Waves = RS row-groups x CS col-groups (CS = WAVES/RS). NT = UDIM/CS/16 is
// the A-reuse factor: MfmaUtil ceiling ~= NT/9.9 (12-cyc CU-shared
// ds_read_b128 vs 4.85-cyc per-SIMD MFMA x4 SIMDs). RS>1 re-reads B from L2
// RS times (WT is L2-resident). B ping-pong prefetch as before.
// ---------------------------------------------------------------------------
template<int ROWS, int UDIM, int KP, int LDA, int WAVES, int RS, bool RELU,
         bool ENDSYNC, typename F>
__device__ __forceinline__ void mfma_gemm(const h16* sA,
    const h16* __restrict__ WT, const float* __restrict__ bias, F emit)
{
  constexpr int CS = WAVES / RS;
  constexpr int RG = ROWS / RS;              // rows per row-group
  constexpr int RT = RG / 16;
  constexpr int NPW0 = UDIM / CS;
  constexpr int NPW = (NPW0 < 16) ? 16 : NPW0;
  constexpr int NT = NPW / 16;
  constexpr int NSTEPS = KP / 32;
  constexpr int CH0 = (NT >= 8) ? 1 : ((NT >= 4) ? 2 : 4);
  constexpr int CHUNK = (NSTEPS < CH0) ? NSTEPS : CH0;
  constexpr int NCH = (NSTEPS + CHUNK - 1) / CHUNK;
  const int tid = threadIdx.x;
  const int wave = tid >> 6;
  const int lane = tid & 63;
  const int m = lane & 15;
  const int quad = lane >> 4;
  const int wr = wave % RS;
  const int wc = wave / RS;
  const int rbase = wr * RG;
  const int n0 = wc * NPW;
  const bool active = (n0 < UDIM);

  f32x4 acc[RT][NT];
#pragma unroll
  for (int r = 0; r < RT; ++r)
#pragma unroll
    for (int j = 0; j < NT; ++j) acc[r][j] = (f32x4){0.f, 0.f, 0.f, 0.f};
  float bb[NT];

  if (active) {
    const h16* wbase = &WT[(size_t)(n0 + m) * KP + quad * 8];
#pragma unroll
    for (int j = 0; j < NT; ++j) bb[j] = bias[n0 + j * 16 + m];

    f16x8 breg[2][CHUNK][NT];
#pragma unroll
    for (int s = 0; s < CHUNK; ++s)
      if (s < NSTEPS)
#pragma unroll
        for (int j = 0; j < NT; ++j)
          breg[0][s][j] = *(const f16x8*)&wbase[(size_t)j * 16 * KP + s * 32];
    asm volatile("" ::: "memory");

#pragma unroll
    for (int c = 0; c < NCH; ++c) {
      if (c + 1 < NCH) {
#pragma unroll
        for (int s = 0; s < CHUNK; ++s) {
          const int st = (c + 1) * CHUNK + s;
          if (st < NSTEPS)
#pragma unroll
            for (int j = 0; j < NT; ++j)
              breg[(c + 1) & 1][s][j] =
                  *(const f16x8*)&wbase[(size_t)j * 16 * KP + st * 32];
        }
      }
#pragma unroll
      for (int s = 0; s < CHUNK; ++s) {
        const int st = c * CHUNK + s;
        if (st < NSTEPS) {
          const int k0 = st * 32;
#pragma unroll
          for (int r = 0; r < RT; ++r) {
            const f16x8 af = *(const f16x8*)&sA[(rbase + r * 16 + m) * LDA + k0 + quad * 8];
#pragma unroll
            for (int j = 0; j < NT; ++j)
              acc[r][j] = __builtin_amdgcn_mfma_f32_16x16x32_f16(af, breg[c & 1][s][j], acc[r][j], 0, 0, 0);
          }
        }
      }
      asm volatile("" ::: "memory");
    }
  }
  __syncthreads();
  if (active) {
#pragma unroll
    for (int j = 0; j < NT; ++j) {
      const int col = n0 + j * 16 + m;
#pragma unroll
      for (int r = 0; r < RT; ++r)
#pragma unroll
        for (int g = 0; g < 4; ++g) {
          const int row = rbase + r * 16 + quad * 4 + g;
          float v = acc[r][j][g] + bb[j];
          if (RELU) v = reluf(v);
          emit(row, col, v);
        }
    }
  }
  if (ENDSYNC) __syncthreads();
}

// ---------------------------------------------------------------------------
// K0: node encoder via MFMA. 32 nodes/block, 512 thr (grid 1563, last 16).
// ---------------------------------------------------------------------------
__global__ __launch_bounds__(512, 4) void k_nenc(
    const h16* __restrict__ X1P, const h16* __restrict__ X2H,
    const h16* __restrict__ WT, const float* __restrict__ BF,
    h16* __restrict__ XH)
{
  __shared__ __align__(16) h16 sA[32 * 168];
  __shared__ __align__(16) h16 sH[32 * 520];
  const int tid = threadIdx.x;
  const int n0 = blockIdx.x * 32;
  const int remn = NN - n0;
  const int cnt = remn < 32 ? remn : 32;
  const int n = tid >> 4;
  const int q = tid & 15;

  if (n < cnt) {
    const int node = n0 + n;
    if (q < 2)
      *(f16x8*)&sA[n * 168 + q * 8] = *(const f16x8*)&X1P[node * 16 + q * 8];
    else if (q < 4)
      *(f16x8*)&sA[n * 168 + 144 + (q - 2) * 8] = (f16x8){};
    *(f16x8*)&sA[n * 168 + 16 + q * 8] =
        *(const f16x8*)&X2H[(size_t)node * 128 + q * 8];
  }
  __syncthreads();

  mfma_gemm<32, 512, 160, 168, 8, 2, true, true>(sA, WT + OFF_N1, BF,
      [&](int row, int col, float v) { sH[row * 520 + col] = (h16)v; });
  mfma_gemm<32, 128, 512, 520, 8, 2, false, false>(sH, WT + OFF_N2, BF + 512,
      [&](int row, int col, float v) {
        if (row < cnt) XH[(size_t)(n0 + row) * 128 + col] = (h16)v;
      });
}

// ---------------------------------------------------------------------------
// K2: FUSED edge features + e-MLP + msg GEMM + in-block segment reduce.
// Sorted edges: 64/block, 512 thr. GEMM1 RS=2 (RT2/NT4); GEMM2/3 RS=4 (NT4).
// ---------------------------------------------------------------------------
__global__ __launch_bounds__(512, 4) void k_edge_mlp(
    const h16* __restrict__ X1P, const h16* __restrict__ X2H,
    const int* __restrict__ ES, const int* __restrict__ ET,
    const h16* __restrict__ XH, const h16* __restrict__ WT,
    const float* __restrict__ be1, const float* __restrict__ be2,
    const float* __restrict__ bmsg,
    h16* __restrict__ EB, float* __restrict__ AGG)
{
  __shared__ __align__(16) h16 sFeat[64 * 568];
  __shared__ int strg[64];
  const int tid = threadIdx.x;
  const long e0 = (long)blockIdx.x * 64;
  const long rem = (long)EE - e0;
  const int cnt = rem < 64 ? (int)rem : 64;
  const int n = tid >> 3;
  const int q = tid & 7;
  h16* Arow = &sFeat[n * 568];
  f16x8 xsv0 = {}, xsv1 = {};

  if (n < cnt) {
    const int s = ES[e0 + n];
    const int t = ET[e0 + n];
    if (q == 0) strg[n] = t;
    float ds = 0.f, ns = 0.f, nt = 0.f;
    if (q < 2) {
      const f16x8 a = *(const f16x8*)&X1P[s * 16 + q * 8];
      const f16x8 b = *(const f16x8*)&X1P[t * 16 + q * 8];
      ds = dot8(a, b, ds); ns = dot8(a, a, ns); nt = dot8(b, b, nt);
      *(f16x8*)&Arow[512 + q * 8] = absdiff8(a, b);
    }
#pragma unroll
    for (int c = 0; c < 2; ++c) {
      const f16x8 a = *(const f16x8*)&X2H[(size_t)s * 128 + q * 16 + c * 8];
      const f16x8 b = *(const f16x8*)&X2H[(size_t)t * 128 + q * 16 + c * 8];
      ds = dot8(a, b, ds); ns = dot8(a, a, ns); nt = dot8(b, b, nt);
      *(f16x8*)&Arow[384 + q * 16 + c * 8] = absdiff8(a, b);
    }
    ds += __shfl_xor(ds, 1); ds += __shfl_xor(ds, 2); ds += __shfl_xor(ds, 4);
    ns += __shfl_xor(ns, 1); ns += __shfl_xor(ns, 2); ns += __shfl_xor(ns, 4);
    nt += __shfl_xor(nt, 1); nt += __shfl_xor(nt, 2); nt += __shfl_xor(nt, 4);
    if (q == 0)
      Arow[528] = (h16)(ds / (fmaxf(sqrtf(ns), EPSC) * fmaxf(sqrtf(nt), EPSC)));

    float ds2 = 0.f, ns2 = 0.f, nt2 = 0.f;
#pragma unroll
    for (int c = 0; c < 2; ++c) {
      const f16x8 a = *(const f16x8*)&XH[(size_t)s * 128 + q * 16 + c * 8];
      const f16x8 b = *(const f16x8*)&XH[(size_t)t * 128 + q * 16 + c * 8];
      if (c == 0) xsv0 = a; else xsv1 = a;
      ds2 = dot8(a, b, ds2); ns2 = dot8(a, a, ns2); nt2 = dot8(b, b, nt2);
      *(f16x8*)&Arow[q * 16 + c * 8]       = a;
      *(f16x8*)&Arow[128 + q * 16 + c * 8] = b;
      *(f16x8*)&Arow[256 + q * 16 + c * 8] = absdiff8(a, b);
    }
    ds2 += __shfl_xor(ds2, 1); ds2 += __shfl_xor(ds2, 2); ds2 += __shfl_xor(ds2, 4);
    ns2 += __shfl_xor(ns2, 1); ns2 += __shfl_xor(ns2, 2); ns2 += __shfl_xor(ns2, 4);
    nt2 += __shfl_xor(nt2, 1); nt2 += __shfl_xor(nt2, 2); nt2 += __shfl_xor(nt2, 4);
    if (q == 0)
      Arow[529] = (h16)(ds2 / (fmaxf(sqrtf(ns2), EPSC) * fmaxf(sqrtf(nt2), EPSC)));
    for (int j = 530 + q; j < 544; j += 8) Arow[j] = (h16)0.f;
  } else {
    if (q == 0) strg[n] = 0;
    for (int j8 = q; j8 < 71; j8 += 8) *(f16x8*)&Arow[j8 * 8] = (f16x8){};
  }
  __syncthreads();

  h16* sHid = sFeat;   // stride 264, overlays features (post-barrier)
  mfma_gemm<64, 256, 544, 568, 8, 2, true, true>(sFeat, WT + OFF_E1, be1,
      [&](int row, int col, float v) { sHid[row * 264 + col] = (h16)v; });
  mfma_gemm<64, 128, 256, 264, 8, 4, false, false>(sHid, WT + OFF_E2, be2,
      [&](int row, int col, float v) {
        const h16 vh = (h16)v;
        if (row < cnt) EB[(size_t)(e0 + row) * 128 + col] = vh;
        sHid[row * 264 + col] = vh;                // e at cols [0,128)
      });
  // park xs beside e at cols [128,256): same post-A-read window as GEMM2 emit
  *(f16x8*)&sFeat[n * 264 + 128 + q * 16]     = xsv0;
  *(f16x8*)&sFeat[n * 264 + 128 + q * 16 + 8] = xsv1;
  __syncthreads();
  // msg GEMM: emit fp32 into the (dead, post-barrier) A region, stride 528B
  mfma_gemm<64, 128, 256, 264, 8, 4, true, true>(sFeat, WT + OFF_MSG, bmsg,
      [&](int row, int col, float v) {
        *(float*)((char*)sFeat + row * 528 + col * 4) = v;
      });
  // segment reduction: sorted trg -> runs; 4 row-groups x 128 cols
  {
    const int c = tid & 127;
    const int g = tid >> 7;
    const int r0 = g * 16;
    if (r0 < cnt) {
      const int rend = (r0 + 16 < cnt) ? r0 + 16 : cnt;
      float acc = 0.f;
      int cur = strg[r0];
      for (int r = r0; r < rend; ++r) {
        const int t = strg[r];
        if (t != cur) {
          atomicAdd(&AGG[(size_t)cur * 128 + c], acc);
          acc = 0.f; cur = t;
        }
        acc += *(const float*)((const char*)sFeat + r * 528 + c * 4);
      }
      atomicAdd(&AGG[(size_t)cur * 128 + c], acc);
    }
  }
}

// ---------------------------------------------------------------------------
// K3: xn = relu([x|agg] @ Wnode + b). 64 nodes/block. RS=2 -> RT2/NT4.
// ---------------------------------------------------------------------------
__global__ __launch_bounds__(256, 4) void k_node_update(
    const h16* __restrict__ XH, const float* __restrict__ AGG,
    const h16* __restrict__ WT, const float* __restrict__ bnode,
    h16* __restrict__ XNH)
{
  __shared__ __align__(16) h16 sA[64 * 264];
  const int tid = threadIdx.x;
  const int n0 = blockIdx.x * 64;
  const int remn = NN - n0;
  const int cnt = remn < 64 ? remn : 64;
  const int n = tid >> 2;
  const int q = tid & 3;

  if (n < cnt) {
    const f16x8* xr = (const f16x8*)&XH[(size_t)(n0 + n) * 128];
    const float4* ar = (const float4*)&AGG[(size_t)(n0 + n) * 128];
    for (int j8 = q; j8 < 16; j8 += 4)
      *(f16x8*)&sA[n * 264 + j8 * 8] = xr[j8];
    for (int j4 = q; j4 < 32; j4 += 4) {
      const float4 b = ar[j4];
      h16* p1 = &sA[n * 264 + 128 + j4 * 4];
      p1[0] = (h16)b.x; p1[1] = (h16)b.y; p1[2] = (h16)b.z; p1[3] = (h16)b.w;
    }
  } else {
    for (int j = q; j < 256; j += 4) sA[n * 264 + j] = (h16)0.f;
  }
  __syncthreads();

  mfma_gemm<64, 128, 256, 264, 4, 2, true, false>(sA, WT + OFF_NODE, bnode,
      [&](int row, int col, float v) {
        if (row < cnt) XNH[(size_t)(n0 + row) * 128 + col] = (h16)v;
      });
}

// ---------------------------------------------------------------------------
// K4: e_mp MLP + classifier, sorted edge order; out scattered via OID.
// MP1 RS=2 (RT2/NT4); MP2/C1 RS=4.
// ---------------------------------------------------------------------------
__global__ __launch_bounds__(512, 4) void k_empl(
    const int* __restrict__ ES, const int* __restrict__ ET,
    const int* __restrict__ OID, const h16* __restrict__ XNH,
    const h16* __restrict__ EB, const h16* __restrict__ WT,
    const float* __restrict__ bmp1, const float* __restrict__ bmp2,
    const float* __restrict__ bc1,
    const float* __restrict__ Wc2, const float* __restrict__ bc2,
    float* __restrict__ out)
{
  __shared__ __align__(16) h16 sF[64 * 392];
  const int tid = threadIdx.x;
  const long e0 = (long)blockIdx.x * 64;
  const long rem = (long)EE - e0;
  const int cnt = rem < 64 ? (int)rem : 64;
  const int n = tid >> 3;
  const int q = tid & 7;

  if (n < cnt) {
    const int s = ES[e0 + n];
    const int t = ET[e0 + n];
    const f16x8* xsr = (const f16x8*)&XNH[(size_t)s * 128];
    const f16x8* xtr = (const f16x8*)&XNH[(size_t)t * 128];
    const f16x8* ebr = (const f16x8*)&EB[(size_t)(e0 + n) * 128];
#pragma unroll
    for (int j8 = q; j8 < 16; j8 += 8) {
      *(f16x8*)&sF[n * 392 + j8 * 8]       = xsr[j8];
      *(f16x8*)&sF[n * 392 + 128 + j8 * 8] = xtr[j8];
      *(f16x8*)&sF[n * 392 + 256 + j8 * 8] = ebr[j8];
    }
  } else {
    for (int j8 = q; j8 < 49; j8 += 8) *(f16x8*)&sF[n * 392 + j8 * 8] = (f16x8){};
  }
  __syncthreads();

  h16*  sH2 = sF;                              // stride 264
  h16*  sE  = sF;                              // stride 136 (over dead H2)
  float* sHC = (float*)((char*)sF + 17408);    // stride 65 fp32, disjoint
  mfma_gemm<64, 256, 384, 392, 8, 2, true, true>(sF, WT + OFF_MP1, bmp1,
      [&](int row, int col, float v) { sH2[row * 264 + col] = (h16)v; });
  mfma_gemm<64, 128, 256, 264, 8, 4, false, true>(sH2, WT + OFF_MP2, bmp2,
      [&](int row, int col, float v) { sE[row * 136 + col] = (h16)v; });
  mfma_gemm<64, 64, 128, 136, 8, 4, true, true>(sE, WT + OFF_C1, bc1,
      [&](int row, int col, float v) { sHC[row * 65 + col] = v; });
  if (tid < cnt) {
    float acc = bc2[0];
    for (int k = 0; k < 64; ++k) acc += sHC[tid * 65 + k] * Wc2[k];
    out[OID[e0 + tid]] = acc;
  }
}

// ---------------------------------------------------------------------------
extern "C" void kernel_launch(void* const* d_in, const int* in_sizes, int n_in,
                              void* d_out, int out_size, void* d_ws, size_t ws_size,
                              hipStream_t stream)
{
  const float* x1  = (const float*)d_in[0];
  const float* x2  = (const float*)d_in[1];
  const int*   ei  = (const int*)d_in[2];
  const float* Wh1 = (const float*)d_in[3],  *bh1 = (const float*)d_in[4];
  const float* Wh2 = (const float*)d_in[5],  *bh2 = (const float*)d_in[6];
  const float* Wl1 = (const float*)d_in[7],  *bl1 = (const float*)d_in[8];
  const float* Wl2 = (const float*)d_in[9],  *bl2 = (const float*)d_in[10];
  const float* We1 = (const float*)d_in[11], *be1 = (const float*)d_in[12];
  const float* We2 = (const float*)d_in[13], *be2 = (const float*)d_in[14];
  const float* Wmsg = (const float*)d_in[15], *bmsg = (const float*)d_in[16];
  const float* Wnode = (const float*)d_in[17], *bnode = (const float*)d_in[18];
  const float* Wmp1 = (const float*)d_in[19], *bmp1 = (const float*)d_in[20];
  const float* Wmp2 = (const float*)d_in[21], *bmp2 = (const float*)d_in[22];
  const float* Wc1 = (const float*)d_in[23], *bc1 = (const float*)d_in[24];
  const float* Wc2 = (const float*)d_in[25], *bc2 = (const float*)d_in[26];
  float* out = (float*)d_out;

  // ws layout (~201MB): AGG|EB|WT|XH|XNH|X1P|X2H|BF|CNT|POS|TEX|ES|ET|OID|BS|BSSE
  float* AGG = (float*)d_ws;
  h16*   EB  = (h16*)(AGG + (size_t)NN * 128);
  h16*   WT  = EB + (size_t)EE * 128;
  h16*   XH  = WT + WT_TOTAL;
  h16*   XNH = XH + (size_t)NN * 128;
  h16*   X1P = XNH + (size_t)NN * 128;
  h16*   X2H = X1P + (size_t)NN * 16;
  float* BF  = (float*)(X2H + (size_t)NN * 128);
  int*   CNT = (int*)(BF + BF_TOTAL);
  int*   POS = CNT + NN;
  int*   TEX = POS + NN;
  int*   ES  = TEX + NN;
  int*   ET  = ES + EE;
  int*   OID = ET + EE;
  int*   BS  = OID + EE;
  int*   BSSE = BS + 256;

  k_prep<<<(WT_TOTAL + BF_TOTAL + 255) / 256, 256, 0, stream>>>(
      We1, We2, Wmsg, Wnode, Wmp1, Wmp2, Wc1,
      Wh1, Wl1, Wh2, Wl2, bh1, bl1, bh2, bl2, WT, BF);
  hipMemsetAsync(AGG, 0, (size_t)NN * 128 * sizeof(float), stream);
  hipMemsetAsync(CNT, 0, (size_t)2 * NN * sizeof(int), stream);  // CNT+POS
  k_cvt<<<(NN * 16 + NN * 128 + 255) / 256, 256, 0, stream>>>(
      x1, x2, ei, X1P, X2H, CNT);
  k_scanA<<<SCAN_B, 256, 0, stream>>>(CNT, TEX, BS);
  k_scanB<<<1, 256, 0, stream>>>(BS, BSSE);
  k_scatter<<<(EE + 255) / 256, 256, 0, stream>>>(ei, TEX, BSSE, POS, ES, ET, OID);
  k_nenc<<<(NN + 31) / 32, 512, 0, stream>>>(X1P, X2H, WT, BF, XH);
  k_edge_mlp<<<7813, 512, 0, stream>>>(X1P, X2H, ES, ET, XH, WT,
                                       be1, be2, bmsg, EB, AGG);
  k_node_update<<<782, 256, 0, stream>>>(XH, AGG, WT, bnode, XNH);
  k_empl<<<7813, 512, 0, stream>>>(ES, ET, OID, XNH, EB, WT, bmp1, bmp2, bc1,
                                   Wc2, bc2, out);
}

// Round 9
// 881.508 us; speedup vs baseline: 1.9085x; 1.9085x over previous
//
#include <hip/hip_runtime.h>
#include <hip/hip_bf16.h>
#include <hip/hip_fp16.h>

// CellTrack GNN, MI355X — R22: 128-edge/1024-thr blocks (B-traffic amortize).
// R21 (1682us) refuted LDS-BW theory: RS halved LDS reads but x2.6 B traffic
// -> 2.1x slower. Fit: dur = 112us + 41.3us * (B KB/edge) -> kernel is bound
// by B-operand L2 latency*concurrency. Only lever: more edges per block.
// R22: k_edge_mlp/k_empl 128 edges/block, 1024 thr, 16 waves, RS=1:
// B/edge 6.34->3.17 and 4.25->2.13 KB. LDS 143/98KB -> 1 blk/CU, still 16
// waves (50% occ). 128-wide GEMMs idle 8/16 waves in k-loop (work unchanged).
// nenc/node_update back to R20 shapes.
// ws: AGG|EB|WT|XH|XNH|X1P|X2H|BF|CNT|POS|TEX|ES|ET|OID|BS|BSSE ~201MB.

using fp16 = __half;
typedef _Float16 h16;
typedef _Float16 f16x8 __attribute__((ext_vector_type(8)));
typedef _Float16 h16x2 __attribute__((ext_vector_type(2)));
typedef short s16x8 __attribute__((ext_vector_type(8)));
typedef float f32x4 __attribute__((ext_vector_type(4)));

#define NN 50000
#define EE 500000
#define EPSC 1e-8f
#define SCAN_B 196   // ceil(NN/256)

__device__ __forceinline__ float reluf(float v){ return v > 0.f ? v : 0.f; }

__device__ __forceinline__ float dot8(const f16x8 a, const f16x8 b, float acc)
{
#pragma unroll
  for (int i = 0; i < 4; ++i) {
    const h16x2 av = {a[2 * i], a[2 * i + 1]};
    const h16x2 bv = {b[2 * i], b[2 * i + 1]};
    acc = __builtin_amdgcn_fdot2(av, bv, acc, false);
  }
  return acc;
}

__device__ __forceinline__ f16x8 absdiff8(const f16x8 a, const f16x8 b)
{
  const f16x8 d = a - b;
  s16x8 di = __builtin_bit_cast(s16x8, d);
  di &= (short)0x7fff;
  return __builtin_bit_cast(f16x8, di);
}

// WT sub-buffer offsets (halves)
#define OFF_E1   0         // [256][544]  (527 real, permuted col order)
#define OFF_E2   139264    // [128][256]
#define OFF_MSG  172032    // [128][256]  ([e|xs] order)
#define OFF_NODE 204800    // [128][256]
#define OFF_MP1  237568    // [256][384]
#define OFF_MP2  335872    // [128][256]
#define OFF_C1   368640    // [64][128]
#define OFF_N1   376832    // [512][160]  block-diag [Wh1 | Wl1]
#define OFF_N2   458752    // [128][512]  block-diag [Wh2 ; Wl2]
#define WT_TOTAL 524288
#define BF_TOTAL 640

// ---------------------------------------------------------------------------
__global__ __launch_bounds__(256) void k_prep(
    const float* __restrict__ We1, const float* __restrict__ We2,
    const float* __restrict__ Wmsg, const float* __restrict__ Wnode,
    const float* __restrict__ Wmp1, const float* __restrict__ Wmp2,
    const float* __restrict__ Wc1,
    const float* __restrict__ Wh1, const float* __restrict__ Wl1,
    const float* __restrict__ Wh2, const float* __restrict__ Wl2,
    const float* __restrict__ bh1, const float* __restrict__ bl1,
    const float* __restrict__ bh2, const float* __restrict__ bl2,
    h16* __restrict__ WT, float* __restrict__ BF)
{
  int idx = blockIdx.x * 256 + threadIdx.x;
  if (idx >= WT_TOTAL) {
    const int b = idx - WT_TOTAL;
    if (b < 512) BF[b] = (b < 256) ? bh1[b] : bl1[b - 256];
    else if (b < BF_TOTAL) {
      const int c = b - 512;
      BF[b] = (c < 32) ? bh2[c] : bl2[c - 32];
    }
    return;
  }
  h16 v;
  if (idx < OFF_E2) {
    const int L = idx, n = L / 544, k = L % 544;
    int r;
    if      (k < 128) r = 142 + k;
    else if (k < 256) r = 270 + (k - 128);
    else if (k < 384) r = 398 + (k - 256);
    else if (k < 512) r = 13 + (k - 384);
    else if (k < 525) r = k - 512;
    else if (k == 528) r = 141;
    else if (k == 529) r = 526;
    else r = -1;
    v = (h16)((r >= 0) ? We1[r * 256 + n] : 0.f);
  } else if (idx < OFF_MSG) {
    const int L = idx - OFF_E2, n = L >> 8, k = L & 255;
    v = (h16)We2[k * 128 + n];
  } else if (idx < OFF_NODE) {
    const int L = idx - OFF_MSG, n = L >> 8, k = L & 255;
    const int ko = (k < 128) ? (128 + k) : (k - 128);   // [e|xs] order
    v = (h16)Wmsg[ko * 128 + n];
  } else if (idx < OFF_MP1) {
    const int L = idx - OFF_NODE, n = L >> 8, k = L & 255;
    v = (h16)Wnode[k * 128 + n];
  } else if (idx < OFF_MP2) {
    const int L = idx - OFF_MP1, n = L / 384, k = L % 384;
    v = (h16)Wmp1[k * 256 + n];
  } else if (idx < OFF_C1) {
    const int L = idx - OFF_MP2, n = L >> 8, k = L & 255;
    v = (h16)Wmp2[k * 128 + n];
  } else if (idx < OFF_N1) {
    const int L = idx - OFF_C1, n = L >> 7, k = L & 127;
    v = (h16)Wc1[k * 64 + n];
  } else if (idx < OFF_N2) {
    const int L = idx - OFF_N1, n = L / 160, k = L % 160;
    float f = 0.f;
    if (n < 256) { if (k < 13) f = Wh1[k * 256 + n]; }
    else { if (k >= 16 && k < 144) f = Wl1[(k - 16) * 256 + (n - 256)]; }
    v = (h16)f;
  } else {
    const int L = idx - OFF_N2, n = L >> 9, k = L & 511;
    float f = 0.f;
    if (n < 32) { if (k < 256) f = Wh2[k * 32 + n]; }
    else { if (k >= 256) f = Wl2[(k - 256) * 96 + (n - 32)]; }
    v = (h16)f;
  }
  WT[idx] = v;
}

// k_cvt: x1 -> fp16 mirror padded to 16/row, x2 -> fp16; + trg histogram.
__global__ __launch_bounds__(256) void k_cvt(
    const float* __restrict__ x1, const float* __restrict__ x2,
    const int* __restrict__ ei,
    h16* __restrict__ X1P, h16* __restrict__ X2H, int* __restrict__ CNT)
{
  const int idx = blockIdx.x * 256 + threadIdx.x;
  if (idx < EE) atomicAdd(&CNT[ei[EE + idx]], 1);
  if (idx < NN * 16) {
    const int nn = idx >> 4, j = idx & 15;
    X1P[idx] = (h16)((j < 13) ? x1[nn * 13 + j] : 0.f);
  }
  const int i2 = idx - NN * 16;
  if (i2 >= 0 && i2 < NN * 128) X2H[i2] = (h16)x2[i2];
}

// --------------------------- hierarchical scan -----------------------------
__global__ __launch_bounds__(256) void k_scanA(
    const int* __restrict__ CNT, int* __restrict__ TEX, int* __restrict__ BS)
{
  __shared__ int sd[256];
  const int tid = threadIdx.x;
  const int i = blockIdx.x * 256 + tid;
  const int v = (i < NN) ? CNT[i] : 0;
  sd[tid] = v;
  __syncthreads();
  for (int off = 1; off < 256; off <<= 1) {
    const int x = (tid >= off) ? sd[tid - off] : 0;
    __syncthreads();
    sd[tid] += x;
    __syncthreads();
  }
  if (i < NN) TEX[i] = sd[tid] - v;
  if (tid == 255) BS[blockIdx.x] = sd[255];
}

__global__ __launch_bounds__(256) void k_scanB(
    const int* __restrict__ BS, int* __restrict__ BSSE)
{
  __shared__ int sd[256];
  const int tid = threadIdx.x;
  const int v = (tid < SCAN_B) ? BS[tid] : 0;
  sd[tid] = v;
  __syncthreads();
  for (int off = 1; off < 256; off <<= 1) {
    const int x = (tid >= off) ? sd[tid - off] : 0;
    __syncthreads();
    sd[tid] += x;
    __syncthreads();
  }
  if (tid < SCAN_B) BSSE[tid] = sd[tid] - v;
}

__global__ __launch_bounds__(256) void k_scatter(
    const int* __restrict__ ei, const int* __restrict__ TEX,
    const int* __restrict__ BSSE, int* __restrict__ POS,
    int* __restrict__ ES, int* __restrict__ ET, int* __restrict__ OID)
{
  const int e = blockIdx.x * 256 + threadIdx.x;
  if (e >= EE) return;
  const int t = ei[EE + e];
  const int p = atomicAdd(&POS[t], 1);
  const int idx = BSSE[t >> 8] + TEX[t] + p;
  ES[idx] = ei[e];
  ET[idx] = t;
  OID[idx] = e;
}

// ---------------------------------------------------------------------------
// MFMA GEMM: C[ROWS][UDIM] = act(A[ROWS][KP] @ WT^T + b). RS=1 everywhere in
// R22 (R21 proved B L2 traffic binds; RS>1 multiplies it). Waves with
// n0>=UDIM idle through the k-loop but hit barriers.
// ---------------------------------------------------------------------------
template<int ROWS, int UDIM, int KP, int LDA, int WAVES, int RS, bool RELU,
         bool ENDSYNC, typename F>
__device__ __forceinline__ void mfma_gemm(const h16* sA,
    const h16* __restrict__ WT, const float* __restrict__ bias, F emit)
{
  constexpr int CS = WAVES / RS;
  constexpr int RG = ROWS / RS;
  constexpr int RT = RG / 16;
  constexpr int NPW0 = UDIM / CS;
  constexpr int NPW = (NPW0 < 16) ? 16 : NPW0;
  constexpr int NT = NPW / 16;
  constexpr int NSTEPS = KP / 32;
  constexpr int CH0 = (NT >= 8) ? 1 : ((NT >= 4) ? 2 : 4);
  constexpr int CHUNK = (NSTEPS < CH0) ? NSTEPS : CH0;
  constexpr int NCH = (NSTEPS + CHUNK - 1) / CHUNK;
  const int tid = threadIdx.x;
  const int wave = tid >> 6;
  const int lane = tid & 63;
  const int m = lane & 15;
  const int quad = lane >> 4;
  const int wr = wave % RS;
  const int wc = wave / RS;
  const int rbase = wr * RG;
  const int n0 = wc * NPW;
  const bool active = (n0 < UDIM);

  f32x4 acc[RT][NT];
#pragma unroll
  for (int r = 0; r < RT; ++r)
#pragma unroll
    for (int j = 0; j < NT; ++j) acc[r][j] = (f32x4){0.f, 0.f, 0.f, 0.f};
  float bb[NT];

  if (active) {
    const h16* wbase = &WT[(size_t)(n0 + m) * KP + quad * 8];
#pragma unroll
    for (int j = 0; j < NT; ++j) bb[j] = bias[n0 + j * 16 + m];

    f16x8 breg[2][CHUNK][NT];
#pragma unroll
    for (int s = 0; s < CHUNK; ++s)
      if (s < NSTEPS)
#pragma unroll
        for (int j = 0; j < NT; ++j)
          breg[0][s][j] = *(const f16x8*)&wbase[(size_t)j * 16 * KP + s * 32];
    asm volatile("" ::: "memory");

#pragma unroll
    for (int c = 0; c < NCH; ++c) {
      if (c + 1 < NCH) {
#pragma unroll
        for (int s = 0; s < CHUNK; ++s) {
          const int st = (c + 1) * CHUNK + s;
          if (st < NSTEPS)
#pragma unroll
            for (int j = 0; j < NT; ++j)
              breg[(c + 1) & 1][s][j] =
                  *(const f16x8*)&wbase[(size_t)j * 16 * KP + st * 32];
        }
      }
#pragma unroll
      for (int s = 0; s < CHUNK; ++s) {
        const int st = c * CHUNK + s;
        if (st < NSTEPS) {
          const int k0 = st * 32;
#pragma unroll
          for (int r = 0; r < RT; ++r) {
            const f16x8 af = *(const f16x8*)&sA[(rbase + r * 16 + m) * LDA + k0 + quad * 8];
#pragma unroll
            for (int j = 0; j < NT; ++j)
              acc[r][j] = __builtin_amdgcn_mfma_f32_16x16x32_f16(af, breg[c & 1][s][j], acc[r][j], 0, 0, 0);
          }
        }
      }
      asm volatile("" ::: "memory");
    }
  }
  __syncthreads();
  if (active) {
#pragma unroll
    for (int j = 0; j < NT; ++j) {
      const int col = n0 + j * 16 + m;
#pragma unroll
      for (int r = 0; r < RT; ++r)
#pragma unroll
        for (int g = 0; g < 4; ++g) {
          const int row = rbase + r * 16 + quad * 4 + g;
          float v = acc[r][j][g] + bb[j];
          if (RELU) v = reluf(v);
          emit(row, col, v);
        }
    }
  }
  if (ENDSYNC) __syncthreads();
}

// ---------------------------------------------------------------------------
// K0: node encoder via MFMA. 32 nodes/block, 512 thr (R20 shapes).
// ---------------------------------------------------------------------------
__global__ __launch_bounds__(512, 4) void k_nenc(
    const h16* __restrict__ X1P, const h16* __restrict__ X2H,
    const h16* __restrict__ WT, const float* __restrict__ BF,
    h16* __restrict__ XH)
{
  __shared__ __align__(16) h16 sA[32 * 168];
  __shared__ __align__(16) h16 sH[32 * 520];
  const int tid = threadIdx.x;
  const int n0 = blockIdx.x * 32;
  const int remn = NN - n0;
  const int cnt = remn < 32 ? remn : 32;
  const int n = tid >> 4;
  const int q = tid & 15;

  if (n < cnt) {
    const int node = n0 + n;
    if (q < 2)
      *(f16x8*)&sA[n * 168 + q * 8] = *(const f16x8*)&X1P[node * 16 + q * 8];
    else if (q < 4)
      *(f16x8*)&sA[n * 168 + 144 + (q - 2) * 8] = (f16x8){};
    *(f16x8*)&sA[n * 168 + 16 + q * 8] =
        *(const f16x8*)&X2H[(size_t)node * 128 + q * 8];
  }
  __syncthreads();

  mfma_gemm<32, 512, 160, 168, 8, 1, true, true>(sA, WT + OFF_N1, BF,
      [&](int row, int col, float v) { sH[row * 520 + col] = (h16)v; });
  mfma_gemm<32, 128, 512, 520, 8, 1, false, false>(sH, WT + OFF_N2, BF + 512,
      [&](int row, int col, float v) {
        if (row < cnt) XH[(size_t)(n0 + row) * 128 + col] = (h16)v;
      });
}

// ---------------------------------------------------------------------------
// K2: FUSED edge features + e-MLP + msg GEMM + in-block segment reduce.
// 128 sorted edges/block, 1024 thr (16 waves), RS=1. sFeat [128][568] 142KB.
// Grid 3907 (last block 32 edges).
// ---------------------------------------------------------------------------
__global__ __launch_bounds__(1024, 4) void k_edge_mlp(
    const h16* __restrict__ X1P, const h16* __restrict__ X2H,
    const int* __restrict__ ES, const int* __restrict__ ET,
    const h16* __restrict__ XH, const h16* __restrict__ WT,
    const float* __restrict__ be1, const float* __restrict__ be2,
    const float* __restrict__ bmsg,
    h16* __restrict__ EB, float* __restrict__ AGG)
{
  __shared__ __align__(16) h16 sFeat[128 * 568];
  __shared__ int strg[128];
  const int tid = threadIdx.x;
  const long e0 = (long)blockIdx.x * 128;
  const long rem = (long)EE - e0;
  const int cnt = rem < 128 ? (int)rem : 128;
  const int n = tid >> 3;
  const int q = tid & 7;
  h16* Arow = &sFeat[n * 568];
  f16x8 xsv0 = {}, xsv1 = {};

  if (n < cnt) {
    const int s = ES[e0 + n];
    const int t = ET[e0 + n];
    if (q == 0) strg[n] = t;
    float ds = 0.f, ns = 0.f, nt = 0.f;
    if (q < 2) {
      const f16x8 a = *(const f16x8*)&X1P[s * 16 + q * 8];
      const f16x8 b = *(const f16x8*)&X1P[t * 16 + q * 8];
      ds = dot8(a, b, ds); ns = dot8(a, a, ns); nt = dot8(b, b, nt);
      *(f16x8*)&Arow[512 + q * 8] = absdiff8(a, b);
    }
#pragma unroll
    for (int c = 0; c < 2; ++c) {
      const f16x8 a = *(const f16x8*)&X2H[(size_t)s * 128 + q * 16 + c * 8];
      const f16x8 b = *(const f16x8*)&X2H[(size_t)t * 128 + q * 16 + c * 8];
      ds = dot8(a, b, ds); ns = dot8(a, a, ns); nt = dot8(b, b, nt);
      *(f16x8*)&Arow[384 + q * 16 + c * 8] = absdiff8(a, b);
    }
    ds += __shfl_xor(ds, 1); ds += __shfl_xor(ds, 2); ds += __shfl_xor(ds, 4);
    ns += __shfl_xor(ns, 1); ns += __shfl_xor(ns, 2); ns += __shfl_xor(ns, 4);
    nt += __shfl_xor(nt, 1); nt += __shfl_xor(nt, 2); nt += __shfl_xor(nt, 4);
    if (q == 0)
      Arow[528] = (h16)(ds / (fmaxf(sqrtf(ns), EPSC) * fmaxf(sqrtf(nt), EPSC)));

    float ds2 = 0.f, ns2 = 0.f, nt2 = 0.f;
#pragma unroll
    for (int c = 0; c < 2; ++c) {
      const f16x8 a = *(const f16x8*)&XH[(size_t)s * 128 + q * 16 + c * 8];
      const f16x8 b = *(const f16x8*)&XH[(size_t)t * 128 + q * 16 + c * 8];
      if (c == 0) xsv0 = a; else xsv1 = a;
      ds2 = dot8(a, b, ds2); ns2 = dot8(a, a, ns2); nt2 = dot8(b, b, nt2);
      *(f16x8*)&Arow[q * 16 + c * 8]       = a;
      *(f16x8*)&Arow[128 + q * 16 + c * 8] = b;
      *(f16x8*)&Arow[256 + q * 16 + c * 8] = absdiff8(a, b);
    }
    ds2 += __shfl_xor(ds2, 1); ds2 += __shfl_xor(ds2, 2); ds2 += __shfl_xor(ds2, 4);
    ns2 += __shfl_xor(ns2, 1); ns2 += __shfl_xor(ns2, 2); ns2 += __shfl_xor(ns2, 4);
    nt2 += __shfl_xor(nt2, 1); nt2 += __shfl_xor(nt2, 2); nt2 += __shfl_xor(nt2, 4);
    if (q == 0)
      Arow[529] = (h16)(ds2 / (fmaxf(sqrtf(ns2), EPSC) * fmaxf(sqrtf(nt2), EPSC)));
    for (int j = 530 + q; j < 544; j += 8) Arow[j] = (h16)0.f;
  } else {
    if (q == 0) strg[n] = 0;
    for (int j8 = q; j8 < 71; j8 += 8) *(f16x8*)&Arow[j8 * 8] = (f16x8){};
  }
  __syncthreads();

  h16* sHid = sFeat;   // stride 264, overlays features (post-barrier)
  mfma_gemm<128, 256, 544, 568, 16, 1, true, true>(sFeat, WT + OFF_E1, be1,
      [&](int row, int col, float v) { sHid[row * 264 + col] = (h16)v; });
  mfma_gemm<128, 128, 256, 264, 16, 1, false, false>(sHid, WT + OFF_E2, be2,
      [&](int row, int col, float v) {
        const h16 vh = (h16)v;
        if (row < cnt) EB[(size_t)(e0 + row) * 128 + col] = vh;
        sHid[row * 264 + col] = vh;                // e at cols [0,128)
      });
  // park xs beside e at cols [128,256): same post-A-read window as GEMM2 emit
  *(f16x8*)&sFeat[n * 264 + 128 + q * 16]     = xsv0;
  *(f16x8*)&sFeat[n * 264 + 128 + q * 16 + 8] = xsv1;
  __syncthreads();
  // msg GEMM: emit fp32 into the (dead, post-barrier) A region, stride 528B
  mfma_gemm<128, 128, 256, 264, 16, 1, true, true>(sFeat, WT + OFF_MSG, bmsg,
      [&](int row, int col, float v) {
        *(float*)((char*)sFeat + row * 528 + col * 4) = v;
      });
  // segment reduction: sorted trg -> runs; 8 row-groups x 128 cols
  {
    const int c = tid & 127;
    const int g = tid >> 7;
    const int r0 = g * 16;
    if (r0 < cnt) {
      const int rend = (r0 + 16 < cnt) ? r0 + 16 : cnt;
      float acc = 0.f;
      int cur = strg[r0];
      for (int r = r0; r < rend; ++r) {
        const int t = strg[r];
        if (t != cur) {
          atomicAdd(&AGG[(size_t)cur * 128 + c], acc);
          acc = 0.f; cur = t;
        }
        acc += *(const float*)((const char*)sFeat + r * 528 + c * 4);
      }
      atomicAdd(&AGG[(size_t)cur * 128 + c], acc);
    }
  }
}

// ---------------------------------------------------------------------------
// K3: xn = relu([x|agg] @ Wnode + b). 64 nodes/block (R20 shapes).
// ---------------------------------------------------------------------------
__global__ __launch_bounds__(256, 4) void k_node_update(
    const h16* __restrict__ XH, const float* __restrict__ AGG,
    const h16* __restrict__ WT, const float* __restrict__ bnode,
    h16* __restrict__ XNH)
{
  __shared__ __align__(16) h16 sA[64 * 264];
  const int tid = threadIdx.x;
  const int n0 = blockIdx.x * 64;
  const int remn = NN - n0;
  const int cnt = remn < 64 ? remn : 64;
  const int n = tid >> 2;
  const int q = tid & 3;

  if (n < cnt) {
    const f16x8* xr = (const f16x8*)&XH[(size_t)(n0 + n) * 128];
    const float4* ar = (const float4*)&AGG[(size_t)(n0 + n) * 128];
    for (int j8 = q; j8 < 16; j8 += 4)
      *(f16x8*)&sA[n * 264 + j8 * 8] = xr[j8];
    for (int j4 = q; j4 < 32; j4 += 4) {
      const float4 b = ar[j4];
      h16* p1 = &sA[n * 264 + 128 + j4 * 4];
      p1[0] = (h16)b.x; p1[1] = (h16)b.y; p1[2] = (h16)b.z; p1[3] = (h16)b.w;
    }
  } else {
    for (int j = q; j < 256; j += 4) sA[n * 264 + j] = (h16)0.f;
  }
  __syncthreads();

  mfma_gemm<64, 128, 256, 264, 4, 1, true, false>(sA, WT + OFF_NODE, bnode,
      [&](int row, int col, float v) {
        if (row < cnt) XNH[(size_t)(n0 + row) * 128 + col] = (h16)v;
      });
}

// ---------------------------------------------------------------------------
// K4: e_mp MLP + classifier. 128 sorted edges/block, 1024 thr, RS=1.
// sF [128][392] 98KB; overlays: H2 stride 264; e_mp stride 136; HC fp32 at
// byte 34816 (past sE's 34,816B). Grid 3907.
// ---------------------------------------------------------------------------
__global__ __launch_bounds__(1024, 4) void k_empl(
    const int* __restrict__ ES, const int* __restrict__ ET,
    const int* __restrict__ OID, const h16* __restrict__ XNH,
    const h16* __restrict__ EB, const h16* __restrict__ WT,
    const float* __restrict__ bmp1, const float* __restrict__ bmp2,
    const float* __restrict__ bc1,
    const float* __restrict__ Wc2, const float* __restrict__ bc2,
    float* __restrict__ out)
{
  __shared__ __align__(16) h16 sF[128 * 392];
  const int tid = threadIdx.x;
  const long e0 = (long)blockIdx.x * 128;
  const long rem = (long)EE - e0;
  const int cnt = rem < 128 ? (int)rem : 128;
  const int n = tid >> 3;
  const int q = tid & 7;

  if (n < cnt) {
    const int s = ES[e0 + n];
    const int t = ET[e0 + n];
    const f16x8* xsr = (const f16x8*)&XNH[(size_t)s * 128];
    const f16x8* xtr = (const f16x8*)&XNH[(size_t)t * 128];
    const f16x8* ebr = (const f16x8*)&EB[(size_t)(e0 + n) * 128];
#pragma unroll
    for (int j8 = q; j8 < 16; j8 += 8) {
      *(f16x8*)&sF[n * 392 + j8 * 8]       = xsr[j8];
      *(f16x8*)&sF[n * 392 + 128 + j8 * 8] = xtr[j8];
      *(f16x8*)&sF[n * 392 + 256 + j8 * 8] = ebr[j8];
    }
  } else {
    for (int j8 = q; j8 < 49; j8 += 8) *(f16x8*)&sF[n * 392 + j8 * 8] = (f16x8){};
  }
  __syncthreads();

  h16*  sH2 = sF;                              // stride 264
  h16*  sE  = sF;                              // stride 136 (over dead H2)
  float* sHC = (float*)((char*)sF + 34816);    // stride 65 fp32, past sE
  mfma_gemm<128, 256, 384, 392, 16, 1, true, true>(sF, WT + OFF_MP1, bmp1,
      [&](int row, int col, float v) { sH2[row * 264 + col] = (h16)v; });
  mfma_gemm<128, 128, 256, 264, 16, 1, false, true>(sH2, WT + OFF_MP2, bmp2,
      [&](int row, int col, float v) { sE[row * 136 + col] = (h16)v; });
  mfma_gemm<128, 64, 128, 136, 16, 1, true, true>(sE, WT + OFF_C1, bc1,
      [&](int row, int col, float v) { sHC[row * 65 + col] = v; });
  if (tid < cnt) {
    float acc = bc2[0];
    for (int k = 0; k < 64; ++k) acc += sHC[tid * 65 + k] * Wc2[k];
    out[OID[e0 + tid]] = acc;
  }
}

// ---------------------------------------------------------------------------
extern "C" void kernel_launch(void* const* d_in, const int* in_sizes, int n_in,
                              void* d_out, int out_size, void* d_ws, size_t ws_size,
                              hipStream_t stream)
{
  const float* x1  = (const float*)d_in[0];
  const float* x2  = (const float*)d_in[1];
  const int*   ei  = (const int*)d_in[2];
  const float* Wh1 = (const float*)d_in[3],  *bh1 = (const float*)d_in[4];
  const float* Wh2 = (const float*)d_in[5],  *bh2 = (const float*)d_in[6];
  const float* Wl1 = (const float*)d_in[7],  *bl1 = (const float*)d_in[8];
  const float* Wl2 = (const float*)d_in[9],  *bl2 = (const float*)d_in[10];
  const float* We1 = (const float*)d_in[11], *be1 = (const float*)d_in[12];
  const float* We2 = (const float*)d_in[13], *be2 = (const float*)d_in[14];
  const float* Wmsg = (const float*)d_in[15], *bmsg = (const float*)d_in[16];
  const float* Wnode = (const float*)d_in[17], *bnode = (const float*)d_in[18];
  const float* Wmp1 = (const float*)d_in[19], *bmp1 = (const float*)d_in[20];
  const float* Wmp2 = (const float*)d_in[21], *bmp2 = (const float*)d_in[22];
  const float* Wc1 = (const float*)d_in[23], *bc1 = (const float*)d_in[24];
  const float* Wc2 = (const float*)d_in[25], *bc2 = (const float*)d_in[26];
  float* out = (float*)d_out;

  // ws layout (~201MB): AGG|EB|WT|XH|XNH|X1P|X2H|BF|CNT|POS|TEX|ES|ET|OID|BS|BSSE
  float* AGG = (float*)d_ws;
  h16*   EB  = (h16*)(AGG + (size_t)NN * 128);
  h16*   WT  = EB + (size_t)EE * 128;
  h16*   XH  = WT + WT_TOTAL;
  h16*   XNH = XH + (size_t)NN * 128;
  h16*   X1P = XNH + (size_t)NN * 128;
  h16*   X2H = X1P + (size_t)NN * 16;
  float* BF  = (float*)(X2H + (size_t)NN * 128);
  int*   CNT = (int*)(BF + BF_TOTAL);
  int*   POS = CNT + NN;
  int*   TEX = POS + NN;
  int*   ES  = TEX + NN;
  int*   ET  = ES + EE;
  int*   OID = ET + EE;
  int*   BS  = OID + EE;
  int*   BSSE = BS + 256;

  k_prep<<<(WT_TOTAL + BF_TOTAL + 255) / 256, 256, 0, stream>>>(
      We1, We2, Wmsg, Wnode, Wmp1, Wmp2, Wc1,
      Wh1, Wl1, Wh2, Wl2, bh1, bl1, bh2, bl2, WT, BF);
  hipMemsetAsync(AGG, 0, (size_t)NN * 128 * sizeof(float), stream);
  hipMemsetAsync(CNT, 0, (size_t)2 * NN * sizeof(int), stream);  // CNT+POS
  k_cvt<<<(NN * 16 + NN * 128 + 255) / 256, 256, 0, stream>>>(
      x1, x2, ei, X1P, X2H, CNT);
  k_scanA<<<SCAN_B, 256, 0, stream>>>(CNT, TEX, BS);
  k_scanB<<<1, 256, 0, stream>>>(BS, BSSE);
  k_scatter<<<(EE + 255) / 256, 256, 0, stream>>>(ei, TEX, BSSE, POS, ES, ET, OID);
  k_nenc<<<(NN + 31) / 32, 512, 0, stream>>>(X1P, X2H, WT, BF, XH);
  k_edge_mlp<<<3907, 1024, 0, stream>>>(X1P, X2H, ES, ET, XH, WT,
                                        be1, be2, bmsg, EB, AGG);
  k_node_update<<<782, 256, 0, stream>>>(XH, AGG, WT, bnode, XNH);
  k_empl<<<3907, 1024, 0, stream>>>(ES, ET, OID, XNH, EB, WT, bmp1, bmp2, bc1,
                                    Wc2, bc2, out);
}

// Round 10
// 850.694 us; speedup vs baseline: 1.9776x; 1.0362x over previous
//
#include <hip/hip_runtime.h>
#include <hip/hip_bf16.h>
#include <hip/hip_fp16.h>

// CellTrack GNN, MI355X — R23: consolidated hybrid of measured-best configs.
// R22 refuted the pure B-traffic model: B/edge halved but k_edge_mlp 374->422
// (1 blk/CU lost the 2-block phase-slide overlap, m114 mechanism). R21 showed
// B-traffic excess DOES hurt (x2.6 traffic -> x2.1 time). Optimum found:
// k_edge_mlp = R20 shape (64 edges, 512thr, 2 blk/CU, 374us measured);
// k_empl = R22 shape (128 edges, 1024thr, B/edge 2.13KB, helped rest by 34us).
// ws: AGG|EB|WT|XH|XNH|X1P|X2H|BF|CNT|POS|TEX|ES|ET|OID|BS|BSSE ~201MB.

using fp16 = __half;
typedef _Float16 h16;
typedef _Float16 f16x8 __attribute__((ext_vector_type(8)));
typedef _Float16 h16x2 __attribute__((ext_vector_type(2)));
typedef short s16x8 __attribute__((ext_vector_type(8)));
typedef float f32x4 __attribute__((ext_vector_type(4)));

#define NN 50000
#define EE 500000
#define EPSC 1e-8f
#define SCAN_B 196   // ceil(NN/256)

__device__ __forceinline__ float reluf(float v){ return v > 0.f ? v : 0.f; }

__device__ __forceinline__ float dot8(const f16x8 a, const f16x8 b, float acc)
{
#pragma unroll
  for (int i = 0; i < 4; ++i) {
    const h16x2 av = {a[2 * i], a[2 * i + 1]};
    const h16x2 bv = {b[2 * i], b[2 * i + 1]};
    acc = __builtin_amdgcn_fdot2(av, bv, acc, false);
  }
  return acc;
}

__device__ __forceinline__ f16x8 absdiff8(const f16x8 a, const f16x8 b)
{
  const f16x8 d = a - b;
  s16x8 di = __builtin_bit_cast(s16x8, d);
  di &= (short)0x7fff;
  return __builtin_bit_cast(f16x8, di);
}

// WT sub-buffer offsets (halves)
#define OFF_E1   0         // [256][544]  (527 real, permuted col order)
#define OFF_E2   139264    // [128][256]
#define OFF_MSG  172032    // [128][256]  ([e|xs] order)
#define OFF_NODE 204800    // [128][256]
#define OFF_MP1  237568    // [256][384]
#define OFF_MP2  335872    // [128][256]
#define OFF_C1   368640    // [64][128]
#define OFF_N1   376832    // [512][160]  block-diag [Wh1 | Wl1]
#define OFF_N2   458752    // [128][512]  block-diag [Wh2 ; Wl2]
#define WT_TOTAL 524288
#define BF_TOTAL 640

// ---------------------------------------------------------------------------
__global__ __launch_bounds__(256) void k_prep(
    const float* __restrict__ We1, const float* __restrict__ We2,
    const float* __restrict__ Wmsg, const float* __restrict__ Wnode,
    const float* __restrict__ Wmp1, const float* __restrict__ Wmp2,
    const float* __restrict__ Wc1,
    const float* __restrict__ Wh1, const float* __restrict__ Wl1,
    const float* __restrict__ Wh2, const float* __restrict__ Wl2,
    const float* __restrict__ bh1, const float* __restrict__ bl1,
    const float* __restrict__ bh2, const float* __restrict__ bl2,
    h16* __restrict__ WT, float* __restrict__ BF)
{
  int idx = blockIdx.x * 256 + threadIdx.x;
  if (idx >= WT_TOTAL) {
    const int b = idx - WT_TOTAL;
    if (b < 512) BF[b] = (b < 256) ? bh1[b] : bl1[b - 256];
    else if (b < BF_TOTAL) {
      const int c = b - 512;
      BF[b] = (c < 32) ? bh2[c] : bl2[c - 32];
    }
    return;
  }
  h16 v;
  if (idx < OFF_E2) {
    const int L = idx, n = L / 544, k = L % 544;
    int r;
    if      (k < 128) r = 142 + k;
    else if (k < 256) r = 270 + (k - 128);
    else if (k < 384) r = 398 + (k - 256);
    else if (k < 512) r = 13 + (k - 384);
    else if (k < 525) r = k - 512;
    else if (k == 528) r = 141;
    else if (k == 529) r = 526;
    else r = -1;
    v = (h16)((r >= 0) ? We1[r * 256 + n] : 0.f);
  } else if (idx < OFF_MSG) {
    const int L = idx - OFF_E2, n = L >> 8, k = L & 255;
    v = (h16)We2[k * 128 + n];
  } else if (idx < OFF_NODE) {
    const int L = idx - OFF_MSG, n = L >> 8, k = L & 255;
    const int ko = (k < 128) ? (128 + k) : (k - 128);   // [e|xs] order
    v = (h16)Wmsg[ko * 128 + n];
  } else if (idx < OFF_MP1) {
    const int L = idx - OFF_NODE, n = L >> 8, k = L & 255;
    v = (h16)Wnode[k * 128 + n];
  } else if (idx < OFF_MP2) {
    const int L = idx - OFF_MP1, n = L / 384, k = L % 384;
    v = (h16)Wmp1[k * 256 + n];
  } else if (idx < OFF_C1) {
    const int L = idx - OFF_MP2, n = L >> 8, k = L & 255;
    v = (h16)Wmp2[k * 128 + n];
  } else if (idx < OFF_N1) {
    const int L = idx - OFF_C1, n = L >> 7, k = L & 127;
    v = (h16)Wc1[k * 64 + n];
  } else if (idx < OFF_N2) {
    const int L = idx - OFF_N1, n = L / 160, k = L % 160;
    float f = 0.f;
    if (n < 256) { if (k < 13) f = Wh1[k * 256 + n]; }
    else { if (k >= 16 && k < 144) f = Wl1[(k - 16) * 256 + (n - 256)]; }
    v = (h16)f;
  } else {
    const int L = idx - OFF_N2, n = L >> 9, k = L & 511;
    float f = 0.f;
    if (n < 32) { if (k < 256) f = Wh2[k * 32 + n]; }
    else { if (k >= 256) f = Wl2[(k - 256) * 96 + (n - 32)]; }
    v = (h16)f;
  }
  WT[idx] = v;
}

// k_cvt: x1 -> fp16 mirror padded to 16/row, x2 -> fp16; + trg histogram.
__global__ __launch_bounds__(256) void k_cvt(
    const float* __restrict__ x1, const float* __restrict__ x2,
    const int* __restrict__ ei,
    h16* __restrict__ X1P, h16* __restrict__ X2H, int* __restrict__ CNT)
{
  const int idx = blockIdx.x * 256 + threadIdx.x;
  if (idx < EE) atomicAdd(&CNT[ei[EE + idx]], 1);
  if (idx < NN * 16) {
    const int nn = idx >> 4, j = idx & 15;
    X1P[idx] = (h16)((j < 13) ? x1[nn * 13 + j] : 0.f);
  }
  const int i2 = idx - NN * 16;
  if (i2 >= 0 && i2 < NN * 128) X2H[i2] = (h16)x2[i2];
}

// --------------------------- hierarchical scan -----------------------------
__global__ __launch_bounds__(256) void k_scanA(
    const int* __restrict__ CNT, int* __restrict__ TEX, int* __restrict__ BS)
{
  __shared__ int sd[256];
  const int tid = threadIdx.x;
  const int i = blockIdx.x * 256 + tid;
  const int v = (i < NN) ? CNT[i] : 0;
  sd[tid] = v;
  __syncthreads();
  for (int off = 1; off < 256; off <<= 1) {
    const int x = (tid >= off) ? sd[tid - off] : 0;
    __syncthreads();
    sd[tid] += x;
    __syncthreads();
  }
  if (i < NN) TEX[i] = sd[tid] - v;
  if (tid == 255) BS[blockIdx.x] = sd[255];
}

__global__ __launch_bounds__(256) void k_scanB(
    const int* __restrict__ BS, int* __restrict__ BSSE)
{
  __shared__ int sd[256];
  const int tid = threadIdx.x;
  const int v = (tid < SCAN_B) ? BS[tid] : 0;
  sd[tid] = v;
  __syncthreads();
  for (int off = 1; off < 256; off <<= 1) {
    const int x = (tid >= off) ? sd[tid - off] : 0;
    __syncthreads();
    sd[tid] += x;
    __syncthreads();
  }
  if (tid < SCAN_B) BSSE[tid] = sd[tid] - v;
}

__global__ __launch_bounds__(256) void k_scatter(
    const int* __restrict__ ei, const int* __restrict__ TEX,
    const int* __restrict__ BSSE, int* __restrict__ POS,
    int* __restrict__ ES, int* __restrict__ ET, int* __restrict__ OID)
{
  const int e = blockIdx.x * 256 + threadIdx.x;
  if (e >= EE) return;
  const int t = ei[EE + e];
  const int p = atomicAdd(&POS[t], 1);
  const int idx = BSSE[t >> 8] + TEX[t] + p;
  ES[idx] = ei[e];
  ET[idx] = t;
  OID[idx] = e;
}

// ---------------------------------------------------------------------------
// MFMA GEMM: C[ROWS][UDIM] = act(A[ROWS][KP] @ WT^T + b). RS=1 everywhere
// (R21: RS>1 multiplies B L2 traffic -> regression). Waves with n0>=UDIM
// idle through the k-loop but hit barriers.
// ---------------------------------------------------------------------------
template<int ROWS, int UDIM, int KP, int LDA, int WAVES, int RS, bool RELU,
         bool ENDSYNC, typename F>
__device__ __forceinline__ void mfma_gemm(const h16* sA,
    const h16* __restrict__ WT, const float* __restrict__ bias, F emit)
{
  constexpr int CS = WAVES / RS;
  constexpr int RG = ROWS / RS;
  constexpr int RT = RG / 16;
  constexpr int NPW0 = UDIM / CS;
  constexpr int NPW = (NPW0 < 16) ? 16 : NPW0;
  constexpr int NT = NPW / 16;
  constexpr int NSTEPS = KP / 32;
  constexpr int CH0 = (NT >= 8) ? 1 : ((NT >= 4) ? 2 : 4);
  constexpr int CHUNK = (NSTEPS < CH0) ? NSTEPS : CH0;
  constexpr int NCH = (NSTEPS + CHUNK - 1) / CHUNK;
  const int tid = threadIdx.x;
  const int wave = tid >> 6;
  const int lane = tid & 63;
  const int m = lane & 15;
  const int quad = lane >> 4;
  const int wr = wave % RS;
  const int wc = wave / RS;
  const int rbase = wr * RG;
  const int n0 = wc * NPW;
  const bool active = (n0 < UDIM);

  f32x4 acc[RT][NT];
#pragma unroll
  for (int r = 0; r < RT; ++r)
#pragma unroll
    for (int j = 0; j < NT; ++j) acc[r][j] = (f32x4){0.f, 0.f, 0.f, 0.f};
  float bb[NT];

  if (active) {
    const h16* wbase = &WT[(size_t)(n0 + m) * KP + quad * 8];
#pragma unroll
    for (int j = 0; j < NT; ++j) bb[j] = bias[n0 + j * 16 + m];

    f16x8 breg[2][CHUNK][NT];
#pragma unroll
    for (int s = 0; s < CHUNK; ++s)
      if (s < NSTEPS)
#pragma unroll
        for (int j = 0; j < NT; ++j)
          breg[0][s][j] = *(const f16x8*)&wbase[(size_t)j * 16 * KP + s * 32];
    asm volatile("" ::: "memory");

#pragma unroll
    for (int c = 0; c < NCH; ++c) {
      if (c + 1 < NCH) {
#pragma unroll
        for (int s = 0; s < CHUNK; ++s) {
          const int st = (c + 1) * CHUNK + s;
          if (st < NSTEPS)
#pragma unroll
            for (int j = 0; j < NT; ++j)
              breg[(c + 1) & 1][s][j] =
                  *(const f16x8*)&wbase[(size_t)j * 16 * KP + st * 32];
        }
      }
#pragma unroll
      for (int s = 0; s < CHUNK; ++s) {
        const int st = c * CHUNK + s;
        if (st < NSTEPS) {
          const int k0 = st * 32;
#pragma unroll
          for (int r = 0; r < RT; ++r) {
            const f16x8 af = *(const f16x8*)&sA[(rbase + r * 16 + m) * LDA + k0 + quad * 8];
#pragma unroll
            for (int j = 0; j < NT; ++j)
              acc[r][j] = __builtin_amdgcn_mfma_f32_16x16x32_f16(af, breg[c & 1][s][j], acc[r][j], 0, 0, 0);
          }
        }
      }
      asm volatile("" ::: "memory");
    }
  }
  __syncthreads();
  if (active) {
#pragma unroll
    for (int j = 0; j < NT; ++j) {
      const int col = n0 + j * 16 + m;
#pragma unroll
      for (int r = 0; r < RT; ++r)
#pragma unroll
        for (int g = 0; g < 4; ++g) {
          const int row = rbase + r * 16 + quad * 4 + g;
          float v = acc[r][j][g] + bb[j];
          if (RELU) v = reluf(v);
          emit(row, col, v);
        }
    }
  }
  if (ENDSYNC) __syncthreads();
}

// ---------------------------------------------------------------------------
// K0: node encoder via MFMA. 32 nodes/block, 512 thr (grid 1563, last 16).
// ---------------------------------------------------------------------------
__global__ __launch_bounds__(512, 4) void k_nenc(
    const h16* __restrict__ X1P, const h16* __restrict__ X2H,
    const h16* __restrict__ WT, const float* __restrict__ BF,
    h16* __restrict__ XH)
{
  __shared__ __align__(16) h16 sA[32 * 168];
  __shared__ __align__(16) h16 sH[32 * 520];
  const int tid = threadIdx.x;
  const int n0 = blockIdx.x * 32;
  const int remn = NN - n0;
  const int cnt = remn < 32 ? remn : 32;
  const int n = tid >> 4;
  const int q = tid & 15;

  if (n < cnt) {
    const int node = n0 + n;
    if (q < 2)
      *(f16x8*)&sA[n * 168 + q * 8] = *(const f16x8*)&X1P[node * 16 + q * 8];
    else if (q < 4)
      *(f16x8*)&sA[n * 168 + 144 + (q - 2) * 8] = (f16x8){};
    *(f16x8*)&sA[n * 168 + 16 + q * 8] =
        *(const f16x8*)&X2H[(size_t)node * 128 + q * 8];
  }
  __syncthreads();

  mfma_gemm<32, 512, 160, 168, 8, 1, true, true>(sA, WT + OFF_N1, BF,
      [&](int row, int col, float v) { sH[row * 520 + col] = (h16)v; });
  mfma_gemm<32, 128, 512, 520, 8, 1, false, false>(sH, WT + OFF_N2, BF + 512,
      [&](int row, int col, float v) {
        if (row < cnt) XH[(size_t)(n0 + row) * 128 + col] = (h16)v;
      });
}

// ---------------------------------------------------------------------------
// K2: FUSED edge features + e-MLP + msg GEMM + in-block segment reduce.
// R20 measured-best shape: 64 sorted edges/block, 512 thr (8 waves), 2 blk/CU
// (phase-slide overlap). Grid 7813.
// ---------------------------------------------------------------------------
__global__ __launch_bounds__(512, 4) void k_edge_mlp(
    const h16* __restrict__ X1P, const h16* __restrict__ X2H,
    const int* __restrict__ ES, const int* __restrict__ ET,
    const h16* __restrict__ XH, const h16* __restrict__ WT,
    const float* __restrict__ be1, const float* __restrict__ be2,
    const float* __restrict__ bmsg,
    h16* __restrict__ EB, float* __restrict__ AGG)
{
  __shared__ __align__(16) h16 sFeat[64 * 568];
  __shared__ int strg[64];
  const int tid = threadIdx.x;
  const long e0 = (long)blockIdx.x * 64;
  const long rem = (long)EE - e0;
  const int cnt = rem < 64 ? (int)rem : 64;
  const int n = tid >> 3;
  const int q = tid & 7;
  h16* Arow = &sFeat[n * 568];
  f16x8 xsv0 = {}, xsv1 = {};

  if (n < cnt) {
    const int s = ES[e0 + n];
    const int t = ET[e0 + n];
    if (q == 0) strg[n] = t;
    float ds = 0.f, ns = 0.f, nt = 0.f;
    if (q < 2) {
      const f16x8 a = *(const f16x8*)&X1P[s * 16 + q * 8];
      const f16x8 b = *(const f16x8*)&X1P[t * 16 + q * 8];
      ds = dot8(a, b, ds); ns = dot8(a, a, ns); nt = dot8(b, b, nt);
      *(f16x8*)&Arow[512 + q * 8] = absdiff8(a, b);
    }
#pragma unroll
    for (int c = 0; c < 2; ++c) {
      const f16x8 a = *(const f16x8*)&X2H[(size_t)s * 128 + q * 16 + c * 8];
      const f16x8 b = *(const f16x8*)&X2H[(size_t)t * 128 + q * 16 + c * 8];
      ds = dot8(a, b, ds); ns = dot8(a, a, ns); nt = dot8(b, b, nt);
      *(f16x8*)&Arow[384 + q * 16 + c * 8] = absdiff8(a, b);
    }
    ds += __shfl_xor(ds, 1); ds += __shfl_xor(ds, 2); ds += __shfl_xor(ds, 4);
    ns += __shfl_xor(ns, 1); ns += __shfl_xor(ns, 2); ns += __shfl_xor(ns, 4);
    nt += __shfl_xor(nt, 1); nt += __shfl_xor(nt, 2); nt += __shfl_xor(nt, 4);
    if (q == 0)
      Arow[528] = (h16)(ds / (fmaxf(sqrtf(ns), EPSC) * fmaxf(sqrtf(nt), EPSC)));

    float ds2 = 0.f, ns2 = 0.f, nt2 = 0.f;
#pragma unroll
    for (int c = 0; c < 2; ++c) {
      const f16x8 a = *(const f16x8*)&XH[(size_t)s * 128 + q * 16 + c * 8];
      const f16x8 b = *(const f16x8*)&XH[(size_t)t * 128 + q * 16 + c * 8];
      if (c == 0) xsv0 = a; else xsv1 = a;
      ds2 = dot8(a, b, ds2); ns2 = dot8(a, a, ns2); nt2 = dot8(b, b, nt2);
      *(f16x8*)&Arow[q * 16 + c * 8]       = a;
      *(f16x8*)&Arow[128 + q * 16 + c * 8] = b;
      *(f16x8*)&Arow[256 + q * 16 + c * 8] = absdiff8(a, b);
    }
    ds2 += __shfl_xor(ds2, 1); ds2 += __shfl_xor(ds2, 2); ds2 += __shfl_xor(ds2, 4);
    ns2 += __shfl_xor(ns2, 1); ns2 += __shfl_xor(ns2, 2); ns2 += __shfl_xor(ns2, 4);
    nt2 += __shfl_xor(nt2, 1); nt2 += __shfl_xor(nt2, 2); nt2 += __shfl_xor(nt2, 4);
    if (q == 0)
      Arow[529] = (h16)(ds2 / (fmaxf(sqrtf(ns2), EPSC) * fmaxf(sqrtf(nt2), EPSC)));
    for (int j = 530 + q; j < 544; j += 8) Arow[j] = (h16)0.f;
  } else {
    if (q == 0) strg[n] = 0;
    for (int j8 = q; j8 < 71; j8 += 8) *(f16x8*)&Arow[j8 * 8] = (f16x8){};
  }
  __syncthreads();

  h16* sHid = sFeat;   // stride 264, overlays features (post-barrier)
  mfma_gemm<64, 256, 544, 568, 8, 1, true, true>(sFeat, WT + OFF_E1, be1,
      [&](int row, int col, float v) { sHid[row * 264 + col] = (h16)v; });
  mfma_gemm<64, 128, 256, 264, 8, 1, false, false>(sHid, WT + OFF_E2, be2,
      [&](int row, int col, float v) {
        const h16 vh = (h16)v;
        if (row < cnt) EB[(size_t)(e0 + row) * 128 + col] = vh;
        sHid[row * 264 + col] = vh;                // e at cols [0,128)
      });
  // park xs beside e at cols [128,256): same post-A-read window as GEMM2 emit
  *(f16x8*)&sFeat[n * 264 + 128 + q * 16]     = xsv0;
  *(f16x8*)&sFeat[n * 264 + 128 + q * 16 + 8] = xsv1;
  __syncthreads();
  // msg GEMM: emit fp32 into the (dead, post-barrier) A region, stride 528B
  mfma_gemm<64, 128, 256, 264, 8, 1, true, true>(sFeat, WT + OFF_MSG, bmsg,
      [&](int row, int col, float v) {
        *(float*)((char*)sFeat + row * 528 + col * 4) = v;
      });
  // segment reduction: sorted trg -> runs; 4 row-groups x 128 cols
  {
    const int c = tid & 127;
    const int g = tid >> 7;
    const int r0 = g * 16;
    if (r0 < cnt) {
      const int rend = (r0 + 16 < cnt) ? r0 + 16 : cnt;
      float acc = 0.f;
      int cur = strg[r0];
      for (int r = r0; r < rend; ++r) {
        const int t = strg[r];
        if (t != cur) {
          atomicAdd(&AGG[(size_t)cur * 128 + c], acc);
          acc = 0.f; cur = t;
        }
        acc += *(const float*)((const char*)sFeat + r * 528 + c * 4);
      }
      atomicAdd(&AGG[(size_t)cur * 128 + c], acc);
    }
  }
}

// ---------------------------------------------------------------------------
// K3: xn = relu([x|agg] @ Wnode + b). 64 nodes/block.
// ---------------------------------------------------------------------------
__global__ __launch_bounds__(256, 4) void k_node_update(
    const h16* __restrict__ XH, const float* __restrict__ AGG,
    const h16* __restrict__ WT, const float* __restrict__ bnode,
    h16* __restrict__ XNH)
{
  __shared__ __align__(16) h16 sA[64 * 264];
  const int tid = threadIdx.x;
  const int n0 = blockIdx.x * 64;
  const int remn = NN - n0;
  const int cnt = remn < 64 ? remn : 64;
  const int n = tid >> 2;
  const int q = tid & 3;

  if (n < cnt) {
    const f16x8* xr = (const f16x8*)&XH[(size_t)(n0 + n) * 128];
    const float4* ar = (const float4*)&AGG[(size_t)(n0 + n) * 128];
    for (int j8 = q; j8 < 16; j8 += 4)
      *(f16x8*)&sA[n * 264 + j8 * 8] = xr[j8];
    for (int j4 = q; j4 < 32; j4 += 4) {
      const float4 b = ar[j4];
      h16* p1 = &sA[n * 264 + 128 + j4 * 4];
      p1[0] = (h16)b.x; p1[1] = (h16)b.y; p1[2] = (h16)b.z; p1[3] = (h16)b.w;
    }
  } else {
    for (int j = q; j < 256; j += 4) sA[n * 264 + j] = (h16)0.f;
  }
  __syncthreads();

  mfma_gemm<64, 128, 256, 264, 4, 1, true, false>(sA, WT + OFF_NODE, bnode,
      [&](int row, int col, float v) {
        if (row < cnt) XNH[(size_t)(n0 + row) * 128 + col] = (h16)v;
      });
}

// ---------------------------------------------------------------------------
// K4: e_mp MLP + classifier. R22 measured-best shape: 128 sorted edges/block,
// 1024 thr, RS=1, B/edge 2.13KB. sF [128][392] 98KB; HC fp32 @byte 34816.
// Grid 3907.
// ---------------------------------------------------------------------------
__global__ __launch_bounds__(1024, 4) void k_empl(
    const int* __restrict__ ES, const int* __restrict__ ET,
    const int* __restrict__ OID, const h16* __restrict__ XNH,
    const h16* __restrict__ EB, const h16* __restrict__ WT,
    const float* __restrict__ bmp1, const float* __restrict__ bmp2,
    const float* __restrict__ bc1,
    const float* __restrict__ Wc2, const float* __restrict__ bc2,
    float* __restrict__ out)
{
  __shared__ __align__(16) h16 sF[128 * 392];
  const int tid = threadIdx.x;
  const long e0 = (long)blockIdx.x * 128;
  const long rem = (long)EE - e0;
  const int cnt = rem < 128 ? (int)rem : 128;
  const int n = tid >> 3;
  const int q = tid & 7;

  if (n < cnt) {
    const int s = ES[e0 + n];
    const int t = ET[e0 + n];
    const f16x8* xsr = (const f16x8*)&XNH[(size_t)s * 128];
    const f16x8* xtr = (const f16x8*)&XNH[(size_t)t * 128];
    const f16x8* ebr = (const f16x8*)&EB[(size_t)(e0 + n) * 128];
#pragma unroll
    for (int j8 = q; j8 < 16; j8 += 8) {
      *(f16x8*)&sF[n * 392 + j8 * 8]       = xsr[j8];
      *(f16x8*)&sF[n * 392 + 128 + j8 * 8] = xtr[j8];
      *(f16x8*)&sF[n * 392 + 256 + j8 * 8] = ebr[j8];
    }
  } else {
    for (int j8 = q; j8 < 49; j8 += 8) *(f16x8*)&sF[n * 392 + j8 * 8] = (f16x8){};
  }
  __syncthreads();

  h16*  sH2 = sF;                              // stride 264
  h16*  sE  = sF;                              // stride 136 (over dead H2)
  float* sHC = (float*)((char*)sF + 34816);    // stride 65 fp32, past sE
  mfma_gemm<128, 256, 384, 392, 16, 1, true, true>(sF, WT + OFF_MP1, bmp1,
      [&](int row, int col, float v) { sH2[row * 264 + col] = (h16)v; });
  mfma_gemm<128, 128, 256, 264, 16, 1, false, true>(sH2, WT + OFF_MP2, bmp2,
      [&](int row, int col, float v) { sE[row * 136 + col] = (h16)v; });
  mfma_gemm<128, 64, 128, 136, 16, 1, true, true>(sE, WT + OFF_C1, bc1,
      [&](int row, int col, float v) { sHC[row * 65 + col] = v; });
  if (tid < cnt) {
    float acc = bc2[0];
    for (int k = 0; k < 64; ++k) acc += sHC[tid * 65 + k] * Wc2[k];
    out[OID[e0 + tid]] = acc;
  }
}

// ---------------------------------------------------------------------------
extern "C" void kernel_launch(void* const* d_in, const int* in_sizes, int n_in,
                              void* d_out, int out_size, void* d_ws, size_t ws_size,
                              hipStream_t stream)
{
  const float* x1  = (const float*)d_in[0];
  const float* x2  = (const float*)d_in[1];
  const int*   ei  = (const int*)d_in[2];
  const float* Wh1 = (const float*)d_in[3],  *bh1 = (const float*)d_in[4];
  const float* Wh2 = (const float*)d_in[5],  *bh2 = (const float*)d_in[6];
  const float* Wl1 = (const float*)d_in[7],  *bl1 = (const float*)d_in[8];
  const float* Wl2 = (const float*)d_in[9],  *bl2 = (const float*)d_in[10];
  const float* We1 = (const float*)d_in[11], *be1 = (const float*)d_in[12];
  const float* We2 = (const float*)d_in[13], *be2 = (const float*)d_in[14];
  const float* Wmsg = (const float*)d_in[15], *bmsg = (const float*)d_in[16];
  const float* Wnode = (const float*)d_in[17], *bnode = (const float*)d_in[18];
  const float* Wmp1 = (const float*)d_in[19], *bmp1 = (const float*)d_in[20];
  const float* Wmp2 = (const float*)d_in[21], *bmp2 = (const float*)d_in[22];
  const float* Wc1 = (const float*)d_in[23], *bc1 = (const float*)d_in[24];
  const float* Wc2 = (const float*)d_in[25], *bc2 = (const float*)d_in[26];
  float* out = (float*)d_out;

  // ws layout (~201MB): AGG|EB|WT|XH|XNH|X1P|X2H|BF|CNT|POS|TEX|ES|ET|OID|BS|BSSE
  float* AGG = (float*)d_ws;
  h16*   EB  = (h16*)(AGG + (size_t)NN * 128);
  h16*   WT  = EB + (size_t)EE * 128;
  h16*   XH  = WT + WT_TOTAL;
  h16*   XNH = XH + (size_t)NN * 128;
  h16*   X1P = XNH + (size_t)NN * 128;
  h16*   X2H = X1P + (size_t)NN * 16;
  float* BF  = (float*)(X2H + (size_t)NN * 128);
  int*   CNT = (int*)(BF + BF_TOTAL);
  int*   POS = CNT + NN;
  int*   TEX = POS + NN;
  int*   ES  = TEX + NN;
  int*   ET  = ES + EE;
  int*   OID = ET + EE;
  int*   BS  = OID + EE;
  int*   BSSE = BS + 256;

  k_prep<<<(WT_TOTAL + BF_TOTAL + 255) / 256, 256, 0, stream>>>(
      We1, We2, Wmsg, Wnode, Wmp1, Wmp2, Wc1,
      Wh1, Wl1, Wh2, Wl2, bh1, bl1, bh2, bl2, WT, BF);
  hipMemsetAsync(AGG, 0, (size_t)NN * 128 * sizeof(float), stream);
  hipMemsetAsync(CNT, 0, (size_t)2 * NN * sizeof(int), stream);  // CNT+POS
  k_cvt<<<(NN * 16 + NN * 128 + 255) / 256, 256, 0, stream>>>(
      x1, x2, ei, X1P, X2H, CNT);
  k_scanA<<<SCAN_B, 256, 0, stream>>>(CNT, TEX, BS);
  k_scanB<<<1, 256, 0, stream>>>(BS, BSSE);
  k_scatter<<<(EE + 255) / 256, 256, 0, stream>>>(ei, TEX, BSSE, POS, ES, ET, OID);
  k_nenc<<<(NN + 31) / 32, 512, 0, stream>>>(X1P, X2H, WT, BF, XH);
  k_edge_mlp<<<7813, 512, 0, stream>>>(X1P, X2H, ES, ET, XH, WT,
                                       be1, be2, bmsg, EB, AGG);
  k_node_update<<<782, 256, 0, stream>>>(XH, AGG, WT, bnode, XNH);
  k_empl<<<3907, 1024, 0, stream>>>(ES, ET, OID, XNH, EB, WT, bmp1, bmp2, bc1,
                                    Wc2, bc2, out);
}